// Round 6
// baseline (293.148 us; speedup 1.0000x reference)
//
#include <hip/hip_runtime.h>
#include <math.h>

// ProbAttention (Informer ProbSparse) — B=8 L=2048 H=8 D=64 u=40
// q/k/v reshape(B,H,L,D) is a flat reinterpretation -> treat as (BH=64, L, D) contiguous.
#define LSEQ 2048
#define DDIM 64
#define UU   40
#define NBH  64
#define NCHUNK 16
#define CROWS  128            // rows per k-chunk (CROWS*NCHUNK == LSEQ)
#define CTX_ELEMS (NBH*UU*DDIM)   // 163840

// 8-lane-group sum via DPP (pure VALU — keeps the LDS pipe free for k-row reads).
__device__ __forceinline__ float grp8_sum(float x) {
  float t;
  t = __int_as_float(__builtin_amdgcn_update_dpp(0, __float_as_int(x), 0xB1, 0xF, 0xF, false));
  x += t;
  t = __int_as_float(__builtin_amdgcn_update_dpp(0, __float_as_int(x), 0x4E, 0xF, 0xF, false));
  x += t;
  t = __int_as_float(__builtin_amdgcn_update_dpp(0, __float_as_int(x), 0x141, 0xF, 0xF, false));
  x += t;
  return x;
}

// ---------------- K0: bin sample indices by 128-row chunk (shared across all bh) ----
// One wave per l. Stable wave-parallel bucket sort via ballot/popcount. [proven R2-R5]
__global__ __launch_bounds__(256) void k0_sort(
    const int* __restrict__ idxs, int* __restrict__ sidx, int* __restrict__ soff) {
  int l = blockIdx.x * 4 + (threadIdx.x >> 6);
  int lane = threadIdx.x & 63;
  int v = 0, c = NCHUNK;              // lanes >= UU get invalid chunk
  if (lane < UU) { v = idxs[l * UU + lane]; c = v >> 7; }   // 128 rows/chunk
  unsigned long long lower = (1ull << lane) - 1ull;
  int base = 0;
#pragma unroll
  for (int cc = 0; cc < NCHUNK; ++cc) {
    unsigned long long m = __ballot(c == cc);
    if (c == cc) {
      int rank = __popcll(m & lower);
      sidx[l * UU + base + rank] = v;
    }
    int cnt = __popcll(m);
    if (lane == cc) soff[l * NCHUNK + cc] = (base << 8) | cnt;
    base += cnt;
  }
}

// ---------------- K12 v8: LDS-chunk gather, 32KB tile, 4 blocks/CU ----------------
// 1024 blocks (bh = b&63, c = b>>6), 512 threads (8 waves), 32KB LDS.
// R4/R5 diagnosis: 86us at 36% occupancy with LDS 63% / VALU 55% busy — latency-
// bound, not throughput-bound. Fixes: (1) halve LDS tile -> 4 blocks/CU = 32
// waves/CU; (2) drop the R4 XOR swizzle — group lanes sub=0..7 already cover all
// 32 banks regardless of row (row*16 float4 = 0 mod 32 banks), so the swizzle
// never changed bank behavior (R4's 7.8M "conflicts" are inherent b128 phasing);
// (3) no rowv clamp (sidx padded by 16); (4) __any() wave-uniform slot skip
// (mean cnt/chunk is now 2.5 -> ~3 of 8 slots die).
// k still read from HBM exactly once (32MB). All 16 chunk-blocks of a bh land on
// XCD bh%8 -> q row re-reads stay L2-local.
__global__ __launch_bounds__(512, 8) void k12_gather(
    const float* __restrict__ q, const float* __restrict__ k,
    const int* __restrict__ sidx, const int* __restrict__ soff,
    float2* __restrict__ Mpart) {
  __shared__ float4 kt[CROWS * 16];   // 32KB, linear row-major
  int b = blockIdx.x;
  int bh = b & 63;
  int c  = b >> 6;
  int t  = threadIdx.x;

  {
    const float4* src = (const float4*)(k + ((size_t)bh * LSEQ + c * CROWS) * DDIM);
#pragma unroll
    for (int j = 0; j < 4; ++j) kt[t + 512 * j] = src[t + 512 * j];
  }
  __syncthreads();

  int w = t >> 6;            // wave 0..7 owns l in [w*256, w*256+256)
  int lane = t & 63;
  int g = lane >> 3;         // group 0..7 (one l each per batch)
  int sub = lane & 7;

#pragma unroll 1
  for (int lb = 0; lb < 256; lb += 8) {
    int l = w * 256 + lb + g;
    const float4* qr = (const float4*)(q + ((size_t)bh * LSEQ + l) * DDIM);
    float4 qa = qr[sub];        // q row bytes [0,128)
    float4 qb = qr[sub + 8];    // q row bytes [128,256)
    int oc   = soff[l * NCHUNK + c];
    int cnt  = oc & 255;
    int base = oc >> 8;
    const int* sp = sidx + l * UU + base;    // sidx padded +16 -> no clamp
    int rowv[8];
#pragma unroll
    for (int s = 0; s < 8; ++s) rowv[s] = sp[s] & (CROWS - 1);
    float mx = -INFINITY, sm = 0.f;
#pragma unroll
    for (int s = 0; s < 8; ++s) {
      if (s == 0 || __any(s < cnt)) {        // wave-uniform skip of dead slots
        if (s < cnt) {                        // group-uniform lane mask
          const float4* kr = kt + rowv[s] * 16;
          float4 a  = kr[sub];
          float4 bq = kr[sub + 8];
          float d = qa.x * a.x + qa.y * a.y + qa.z * a.z + qa.w * a.w
                  + qb.x * bq.x + qb.y * bq.y + qb.z * bq.z + qb.w * bq.w;
          d = grp8_sum(d);                    // group-wide: all 8 lanes active
          mx = fmaxf(mx, d);
          sm += d;
        }
      }
    }
    for (int s = 8; s < cnt; ++s) {           // very rare (P(cnt>8) ~ 5e-4)
      int row = sp[s] & (CROWS - 1);
      const float4* kr = kt + row * 16;
      float4 a  = kr[sub];
      float4 bq = kr[sub + 8];
      float d = qa.x * a.x + qa.y * a.y + qa.z * a.z + qa.w * a.w
              + qb.x * bq.x + qb.y * bq.y + qb.z * bq.z + qb.w * bq.w;
      d = grp8_sum(d);
      mx = fmaxf(mx, d);
      sm += d;
    }
    if (sub == 0) Mpart[((size_t)bh * NCHUNK + c) * LSEQ + l] = make_float2(mx, sm);
  }
}

// ---------------- K3: top-40 per head; combines 16 Mpart chunks during load --------
// desc value, tie -> smaller index (matches jax.lax.top_k stability)
__global__ __launch_bounds__(256) void k3_topk(const float2* __restrict__ Mp,
                                               int* __restrict__ Mtop) {
  int bh = blockIdx.x;
  int t = threadIdx.x;
  int w = t >> 6;
  int lane = t & 63;
  float v[8];
#pragma unroll
  for (int j = 0; j < 8; ++j) {
    int l = t + 256 * j;
    float mxv = -INFINITY, smv = 0.f;
#pragma unroll
    for (int c = 0; c < NCHUNK; ++c) {
      float2 p = Mp[((size_t)bh * NCHUNK + c) * LSEQ + l];
      mxv = fmaxf(mxv, p.x);
      smv += p.y;
    }
    v[j] = mxv - smv * (1.0f / (float)LSEQ);
  }
  __shared__ float swv[4];
  __shared__ int   swi[4];
  __shared__ int   win;
  for (int it = 0; it < UU; ++it) {
    float bv = -INFINITY; int bi = 0x7fffffff;
#pragma unroll
    for (int j = 0; j < 8; ++j) {
      if (v[j] > bv) { bv = v[j]; bi = t + 256 * j; }
    }
#pragma unroll
    for (int off = 32; off > 0; off >>= 1) {
      float ov = __shfl_xor(bv, off, 64);
      int   oi = __shfl_xor(bi, off, 64);
      if (ov > bv || (ov == bv && oi < bi)) { bv = ov; bi = oi; }
    }
    if (lane == 0) { swv[w] = bv; swi[w] = bi; }
    __syncthreads();
    if (t == 0) {
      float fv = swv[0]; int fi = swi[0];
#pragma unroll
      for (int j = 1; j < 4; ++j) {
        if (swv[j] > fv || (swv[j] == fv && swi[j] < fi)) { fv = swv[j]; fi = swi[j]; }
      }
      Mtop[bh * UU + it] = fi;
      win = fi;
    }
    __syncthreads();
    int wi = win;
#pragma unroll
    for (int j = 0; j < 8; ++j)
      if (wi == t + 256 * j) v[j] = -INFINITY;   // static index, predicated
  }
}

// ---------------- K457: scores + softmax + CONTEXT, fully fused [proven R5] --------
// 640 blocks: bh = b&63, ug = b>>6 (4 u each). LDS = sct 32KB + vtile 16KB = 48KB
// -> 3 blocks/CU. Unchanged from R5 (one-variable discipline this round).
__global__ __launch_bounds__(256, 3) void k457_fused(
    const float* __restrict__ q, const float* __restrict__ k,
    const float* __restrict__ v, const int* __restrict__ Mtop,
    float* __restrict__ attn, float* __restrict__ ctx) {
  __shared__ float  sct[4 * LSEQ];     // 32KB, [u][l]: scores -> normalized attn
  __shared__ float4 vt4[64 * 16];      // 16KB v tile (swizzled); reused as pacc
  int b = blockIdx.x;
  int bh = b & 63;
  int u0 = (b >> 6) * 4;
  int t = threadIdx.x;

  // ---- phase A: scores (R0-proven 4-lane geometry) ----
  {
    int g = t >> 2;
    int sub = t & 3;
    float4 qv[4][4];
#pragma unroll
    for (int u = 0; u < 4; ++u) {
      int qi = Mtop[bh * UU + u0 + u];
      const float4* qr = (const float4*)(q + (size_t)(bh * LSEQ + qi) * DDIM);
#pragma unroll
      for (int m = 0; m < 4; ++m) qv[u][m] = qr[4 * m + sub];
    }
    const float* kb = k + (size_t)bh * LSEQ * DDIM;
#pragma unroll 1
    for (int p = 0; p < 32; ++p) {
      int l = p * 64 + g;
      const float4* kr = (const float4*)(kb + (size_t)l * DDIM);
      float4 ks[4];
#pragma unroll
      for (int m = 0; m < 4; ++m) ks[m] = kr[4 * m + sub];
      float d[4];
#pragma unroll
      for (int u = 0; u < 4; ++u) {
        float s = 0.f;
#pragma unroll
        for (int m = 0; m < 4; ++m) {
          float4 x = qv[u][m], a = ks[m];
          s += x.x * a.x + x.y * a.y + x.z * a.z + x.w * a.w;
        }
        s += __shfl_xor(s, 1, 64);
        s += __shfl_xor(s, 2, 64);
        d[u] = s * 0.125f;
      }
      if (sub == 0) {
#pragma unroll
        for (int u = 0; u < 4; ++u) sct[u * LSEQ + l] = d[u];
      }
    }
  }
  __syncthreads();

  // ---- softmax: wave w owns u-row w; write normalized to sct AND attn ----
  int w = t >> 6, lane = t & 63;
  {
    float* row = sct + w * LSEQ;
    float vv[32];
    float mx = -INFINITY;
#pragma unroll
    for (int j = 0; j < 32; ++j) { vv[j] = row[lane + 64 * j]; mx = fmaxf(mx, vv[j]); }
#pragma unroll
    for (int off = 32; off > 0; off >>= 1) mx = fmaxf(mx, __shfl_xor(mx, off, 64));
    float sm = 0.f;
#pragma unroll
    for (int j = 0; j < 32; ++j) { vv[j] = __expf(vv[j] - mx); sm += vv[j]; }
#pragma unroll
    for (int off = 32; off > 0; off >>= 1) sm += __shfl_xor(sm, off, 64);
    float inv = 1.0f / sm;
    float* ap = attn + (size_t)(bh * UU + u0 + w) * LSEQ;
#pragma unroll
    for (int j = 0; j < 32; ++j) {
      float a = vv[j] * inv;
      row[lane + 64 * j] = a;
      ap[lane + 64 * j] = a;
    }
  }
  __syncthreads();

  // ---- phase B: ctx[bh, u0+u, :] = sum_l attn[u][l] * v[bh, l, :] ----
  int dq = lane & 15;        // d-quad: d = dq*4 .. dq*4+3
  int lq = lane >> 4;        // row-slice 0..3
  float4 acc[4];
#pragma unroll
  for (int u = 0; u < 4; ++u) acc[u] = make_float4(0.f, 0.f, 0.f, 0.f);

  const float4* vsrc = (const float4*)(v + (size_t)bh * LSEQ * DDIM);
#pragma unroll 1
  for (int tile = 0; tile < 32; ++tile) {
    // stage 64 v rows, float4-slot swizzle: slot = c4 ^ (row&3)
#pragma unroll
    for (int i = 0; i < 4; ++i) {
      int idx = t + 256 * i;            // float4 index in tile (0..1023)
      int row = idx >> 4, c4 = idx & 15;
      vt4[row * 16 + (c4 ^ (row & 3))] = vsrc[tile * 1024 + idx];
    }
    __syncthreads();
#pragma unroll
    for (int i = 0; i < 4; ++i) {
      int r = w * 16 + i * 4 + lq;      // row in tile; wave w owns rows w*16..+16
      int l = tile * 64 + r;
      float4 vv4 = vt4[r * 16 + (dq ^ (r & 3))];   // 4 lq -> 4 distinct bank sets
#pragma unroll
      for (int u = 0; u < 4; ++u) {
        float a = sct[u * LSEQ + l];    // 4 distinct addrs/wave, 16-way broadcast
        acc[u].x += a * vv4.x;
        acc[u].y += a * vv4.y;
        acc[u].z += a * vv4.z;
        acc[u].w += a * vv4.w;
      }
    }
    __syncthreads();                    // protect vt4 before next stage
  }

  // reduce partials over lq (lane bits 4,5) — dq position preserved
#pragma unroll
  for (int u = 0; u < 4; ++u) {
    acc[u].x += __shfl_xor(acc[u].x, 16, 64);
    acc[u].y += __shfl_xor(acc[u].y, 16, 64);
    acc[u].z += __shfl_xor(acc[u].z, 16, 64);
    acc[u].w += __shfl_xor(acc[u].w, 16, 64);
    acc[u].x += __shfl_xor(acc[u].x, 32, 64);
    acc[u].y += __shfl_xor(acc[u].y, 32, 64);
    acc[u].z += __shfl_xor(acc[u].z, 32, 64);
    acc[u].w += __shfl_xor(acc[u].w, 32, 64);
  }
  __syncthreads();                      // vt4 free -> reuse as pacc[w][u][64]
  float* pacc = (float*)vt4;
  if (lq == 0) {
#pragma unroll
    for (int u = 0; u < 4; ++u)
      ((float4*)pacc)[(w * 4 + u) * 16 + dq] = acc[u];
  }
  __syncthreads();
  {
    int uu = t >> 6, d = t & 63;
    float s = pacc[(0 * 4 + uu) * 64 + d] + pacc[(1 * 4 + uu) * 64 + d]
            + pacc[(2 * 4 + uu) * 64 + d] + pacc[(3 * 4 + uu) * 64 + d];
    ctx[((size_t)bh * UU + u0 + uu) * DDIM + d] = s;
  }
}

extern "C" void kernel_launch(void* const* d_in, const int* in_sizes, int n_in,
                              void* d_out, int out_size, void* d_ws, size_t ws_size,
                              hipStream_t stream) {
  const float* q   = (const float*)d_in[0];
  const float* k   = (const float*)d_in[1];
  const float* v   = (const float*)d_in[2];
  const int*   idx = (const int*)d_in[3];

  float* ctx  = (float*)d_out;                  // [NBH, UU, DDIM]
  float* attn = (float*)d_out + CTX_ELEMS;      // [NBH, UU, LSEQ]
  // Mpart scratch lives in the attn output region; consumed by k3 BEFORE k457
  // overwrites the region with real attn. NBH*NCHUNK*LSEQ float2 = 4.19M floats
  // < 5.24M available. [proven R2/R4/R5]
  float2* Mpart = (float2*)attn;

  int* sidx = (int*)d_ws;                        // LSEQ*UU + 16 pad = 81936 ints
  int* soff = sidx + LSEQ * UU + 16;             // LSEQ*NCHUNK     = 32768 ints
  int* Mtop = soff + LSEQ * NCHUNK;              // NBH*UU          = 2560 ints

  k0_sort<<<LSEQ / 4, 256, 0, stream>>>(idx, sidx, soff);
  k12_gather<<<NBH * NCHUNK, 512, 0, stream>>>(q, k, sidx, soff, Mpart);
  k3_topk<<<NBH, 256, 0, stream>>>(Mpart, Mtop);
  k457_fused<<<NBH * 10, 256, 0, stream>>>(q, k, v, Mtop, attn, ctx);
}